// Round 10
// baseline (1108.430 us; speedup 1.0000x reference)
//
#include <hip/hip_runtime.h>

#define RR 8
#define DF 128
#define SCAN_B 1024

typedef __attribute__((ext_vector_type(4))) float f32x4;
typedef __attribute__((ext_vector_type(8))) short sv8;
typedef sv8 __attribute__((may_alias)) sv8a;

__device__ __forceinline__ unsigned short bf16r(float f) {
    uint32_t u = __float_as_uint(f);
    u += 0x7fffu + ((u >> 16) & 1u);   // round-to-nearest-even
    return (unsigned short)(u >> 16);
}
__device__ __forceinline__ uint32_t packbf(float lo, float hi) {
    return (uint32_t)bf16r(lo) | ((uint32_t)bf16r(hi) << 16);
}

// ---------------- CSR build (proven) ----------------
__global__ void count_kernel(const int* __restrict__ tgt, const int* __restrict__ et,
                             int* __restrict__ cnt, int E) {
    int e = blockIdx.x * blockDim.x + threadIdx.x;
    if (e < E) atomicAdd(&cnt[tgt[e] * RR + et[e]], 1);
}

__global__ void scan_local(const int* __restrict__ in, int* __restrict__ excl,
                           int* __restrict__ bsum, int n) {
    __shared__ int sm[2][SCAN_B];
    int base = blockIdx.x * SCAN_B;
    for (int t = threadIdx.x; t < SCAN_B; t += 256) {
        int idx = base + t;
        sm[0][t] = (idx < n) ? in[idx] : 0;
    }
    __syncthreads();
    int pin = 0;
    for (int off = 1; off < SCAN_B; off <<= 1) {
        for (int t = threadIdx.x; t < SCAN_B; t += 256) {
            int v = sm[pin][t];
            if (t >= off) v += sm[pin][t - off];
            sm[pin ^ 1][t] = v;
        }
        __syncthreads();
        pin ^= 1;
    }
    for (int t = threadIdx.x; t < SCAN_B; t += 256) {
        int idx = base + t;
        if (idx < n) excl[idx] = sm[pin][t] - in[idx];
    }
    if (threadIdx.x == 0) bsum[blockIdx.x] = sm[pin][SCAN_B - 1];
}

__global__ void scan_bsum(int* __restrict__ bsum, int nb) {
    __shared__ int sm[512];
    for (int t = threadIdx.x; t < nb; t += 256) sm[t] = bsum[t];
    __syncthreads();
    if (threadIdx.x == 0) {
        int run = 0;
        for (int i = 0; i < nb; ++i) { int v = sm[i]; sm[i] = run; run += v; }
    }
    __syncthreads();
    for (int t = threadIdx.x; t < nb; t += 256) bsum[t] = sm[t];
}

__global__ void scan_finish(int* __restrict__ rowptr, const int* __restrict__ bsum,
                            int* __restrict__ cursor, int n, int E) {
    int i = blockIdx.x * blockDim.x + threadIdx.x;
    if (i < n) {
        int v = rowptr[i] + bsum[i / SCAN_B];
        rowptr[i] = v;
        cursor[i] = v;
    }
    if (i == 0) rowptr[n] = E;
}

__global__ void fill_kernel(const int* __restrict__ src, const int* __restrict__ tgt,
                            const int* __restrict__ et, int* __restrict__ cursor,
                            int* __restrict__ es, int E) {
    int e = blockIdx.x * blockDim.x + threadIdx.x;
    if (e < E) {
        int seg = tgt[e] * RR + et[e];
        int pos = atomicAdd(&cursor[seg], 1);
        es[pos] = src[e];
    }
}

// ---------------- f32 [n,2t] -> bf16-pair u32 [n,t] ----------------
__global__ void pack_x_kernel(const float* __restrict__ x, uint32_t* __restrict__ xb,
                              int n64) {
    int t = blockIdx.x * blockDim.x + threadIdx.x;
    if (t < n64) xb[t] = packbf(x[2 * t], x[2 * t + 1]);
}

// ---------------- W packing into MFMA B-fragment order (proven) ----------------
__global__ void pack_w_kernel(const float* __restrict__ W, const float* __restrict__ root,
                              unsigned short* __restrict__ wp, int NT) {
    int tid = blockIdx.x * blockDim.x + threadIdx.x;
    int total = 9 * NT * 2048;
    if (tid >= total) return;
    int i = tid & 7;
    int lane = (tid >> 3) & 63;
    int kk = (tid >> 9) & 3;
    int t = (tid >> 11) % NT;
    int rel = (tid >> 11) / NT;
    int k = kk * 32 + ((lane >> 4) << 3) + i;
    int col = t * 16 + (lane & 15);
    int dout = NT * 16;
    float v = (rel < RR) ? W[((long)rel * DF + k) * dout + col] : root[(long)k * dout + col];
    wp[tid] = bf16r(v);
}

// ---------------- Phase A: XCD-quartered gather-mean ----------------
// Feature dim split in 4 quarters (64B = 1 line per quarter-row). Quarter
// q = blockIdx.x & 3: under round-robin block->XCD dispatch, quarter q runs
// only on XCDs {q, q+4}, shrinking each XCD's gather working set to 3.2MB
// (< 4MB L2). Wave = 4 edge-slots x 16 feature lanes; segment reduction via
// shfl_xor(16/32). Correct under ANY block->XCD mapping (all quarters are
// grid-stride covered); the mapping only affects locality.
__global__ __launch_bounds__(256) void gather_mean_kernel(
    const uint32_t* __restrict__ xb,   // [N,64] bf16 pairs
    const int* __restrict__ es,
    const int* __restrict__ rowptr,    // [N*8+1]
    uint32_t* __restrict__ M,          // [nn*9, 64]
    int n0, int nn) {
    const int lane = threadIdx.x & 63;
    const int q = blockIdx.x & 3;                 // feature quarter
    const int wid = (((blockIdx.x >> 2) * 256 + threadIdx.x) >> 6);
    const int nw = (gridDim.x >> 2) * 4;          // waves per quarter-group
    const int fs = q * 16 + (lane & 15);          // u32 slot within row
    const int esl = lane >> 4;                    // edge slot 0..3
    const int total = nn * 9;
    for (int sid = wid; sid < total; sid += nw) {
        int loc = sid / 9;
        int rel = sid - loc * 9;
        int node = n0 + loc;
        uint32_t outv;
        if (rel == 8) {
            outv = xb[(long)node * 64 + fs];       // root copy (quarter slice)
        } else {
            int seg = node * RR + rel;
            int e0 = rowptr[seg], e1 = rowptr[seg + 1];
            int cnt = e1 - e0;
            float sx = 0.f, sy = 0.f;
            for (int it = 0; it < cnt; it += 4) {
                int idx = e0 + it + esl;
                idx = (idx < e1) ? idx : (e1 - 1);
                int s = es[idx];
                uint32_t u = xb[(long)s * 64 + fs];   // 64B line per edge-slot
                bool ok = (it + esl) < cnt;
                sx += ok ? __uint_as_float(u << 16) : 0.f;
                sy += ok ? __uint_as_float(u & 0xffff0000u) : 0.f;
            }
            sx += __shfl_xor(sx, 16); sy += __shfl_xor(sy, 16);
            sx += __shfl_xor(sx, 32); sy += __shfl_xor(sy, 32);
            float inv = 1.f / fmaxf((float)cnt, 1.f);
            outv = packbf(sx * inv, sy * inv);
        }
        if (lane < 16) M[(long)sid * 64 + fs] = outv;
    }
}

// ---------------- Phase B: pure MFMA transform (proven r8/r9) ----------------
template <int NT, bool RELU>
__global__ __launch_bounds__(256) void gemm_kernel(
    const uint32_t* __restrict__ M,        // [nn*9, 64] bf16 pairs
    const unsigned short* __restrict__ wp, // packed W frags
    const float* __restrict__ bias,        // [NT*16]
    float* __restrict__ out, int n0, int nn) {
    const int wave = threadIdx.x >> 6;
    const int lane = threadIdx.x & 63;
    const int lb = (blockIdx.x * 4 + wave) * 16;   // local node base
    if (lb >= nn) return;
    const int arow = lane & 15;
    const int ag = lane >> 4;

    f32x4 acc[NT];
#pragma unroll
    for (int t = 0; t < NT; ++t) acc[t] = (f32x4){0.f, 0.f, 0.f, 0.f};

    const uint32_t* mrow = M + (long)(lb + arow) * 9 * 64 + ag * 4;

    for (int rel = 0; rel < 9; ++rel) {
        sv8 af[4];   // lane: A[arow][kk*32 + ag*8 .. +7] == 16B at kk*16 u32
#pragma unroll
        for (int kk = 0; kk < 4; ++kk)
            af[kk] = *(const sv8a*)(mrow + rel * 64 + kk * 16);
        const unsigned short* wr = wp + ((long)rel * NT << 11);
#pragma unroll
        for (int t = 0; t < NT; ++t) {
#pragma unroll
            for (int kk = 0; kk < 4; ++kk) {
                sv8 bf = *(const sv8a*)(wr + (((t * 4 + kk) << 9) + (lane << 3)));
                acc[t] = __builtin_amdgcn_mfma_f32_16x16x32_bf16(af[kk], bf, acc[t], 0, 0, 0);
            }
        }
    }

    // epilogue: C/D map col=lane&15, row=4*(lane>>4)+reg (all 16 rows real)
    constexpr int DOUT = NT * 16;
#pragma unroll
    for (int t = 0; t < NT; ++t) {
        int col = t * 16 + arow;
        float bv = bias[col];
#pragma unroll
        for (int reg = 0; reg < 4; ++reg) {
            int row = ag * 4 + reg;
            float v = acc[t][reg] + bv;
            if (RELU) v = fmaxf(v, 0.f);
            out[(long)(n0 + lb + row) * DOUT + col] = v;
        }
    }
}

extern "C" void kernel_launch(void* const* d_in, const int* in_sizes, int n_in,
                              void* d_out, int out_size, void* d_ws, size_t ws_size,
                              hipStream_t stream) {
    const float* xf = (const float*)d_in[0];
    const float* W1 = (const float*)d_in[1];
    const float* r1 = (const float*)d_in[2];
    const float* b1 = (const float*)d_in[3];
    const float* W2 = (const float*)d_in[4];
    const float* r2 = (const float*)d_in[5];
    const float* b2 = (const float*)d_in[6];
    const int* eidx = (const int*)d_in[7];
    const int* etyp = (const int*)d_in[8];
    const int N = in_sizes[0] / DF;
    const int E = in_sizes[8];
    const int* src = eidx;
    const int* tgt = eidx + E;
    const int NR = N * RR;

    // ws layout: cnt[NR] rowptr[NR+16] cursor[NR+16] bsum[512] es[E]
    //   x1f[N*128]f32 xb[N*64]u32 x1b[N*64]u32 wp1 wp2 M[CH*9*64]u32
    int* cnt = (int*)d_ws;
    int* rowptr = cnt + NR;
    int* cursor = rowptr + NR + 16;
    int* bsum = cursor + NR + 16;
    int* es = bsum + 512;
    float* x1f = (float*)(es + E);
    uint32_t* xb = (uint32_t*)(x1f + (size_t)N * DF);
    uint32_t* x1b = xb + (size_t)N * 64;
    unsigned short* wp1 = (unsigned short*)(x1b + (size_t)N * 64);
    unsigned short* wp2 = wp1 + 9 * 8 * 2048;
    uint32_t* M = (uint32_t*)(wp2 + 9 * 4 * 2048);

    size_t used = (size_t)((char*)M - (char*)d_ws);
    size_t avail = (ws_size > used) ? (ws_size - used) : 0;
    int CH = (int)(avail / (9 * 64 * sizeof(uint32_t)));
    CH &= ~63;                       // multiple of 64 (=> chunk mult of 16)
    if (CH > N) CH = ((N + 63) / 64) * 64;
    if (CH > 25600) CH = 25600;      // M <= 59 MB; fewer chunks = better reuse
    if (CH < 64) CH = 64;            // degenerate fallback

    const int nb1 = (NR + SCAN_B - 1) / SCAN_B;

    hipMemsetAsync(cnt, 0, (size_t)NR * sizeof(int), stream);
    count_kernel<<<(E + 255) / 256, 256, 0, stream>>>(tgt, etyp, cnt, E);
    scan_local<<<nb1, 256, 0, stream>>>(cnt, rowptr, bsum, NR);
    scan_bsum<<<1, 256, 0, stream>>>(bsum, nb1);
    scan_finish<<<(NR + 255) / 256, 256, 0, stream>>>(rowptr, bsum, cursor, NR, E);
    fill_kernel<<<(E + 255) / 256, 256, 0, stream>>>(src, tgt, etyp, cursor, es, E);

    pack_x_kernel<<<(N * 64 + 255) / 256, 256, 0, stream>>>(xf, xb, N * 64);
    pack_w_kernel<<<(9 * 8 * 2048 + 255) / 256, 256, 0, stream>>>(W1, r1, wp1, 8);
    pack_w_kernel<<<(9 * 4 * 2048 + 255) / 256, 256, 0, stream>>>(W2, r2, wp2, 4);

    const int GA = 2048;   // 512 blocks per feature-quarter group
    // ---- layer 1 ----
    for (int n0 = 0; n0 < N; n0 += CH) {
        int nn = (N - n0 < CH) ? (N - n0) : CH;
        gather_mean_kernel<<<GA, 256, 0, stream>>>(xb, es, rowptr, M, n0, nn);
        gemm_kernel<8, true><<<((nn + 15) / 16 + 3) / 4, 256, 0, stream>>>(
            M, wp1, b1, x1f, n0, nn);
    }
    pack_x_kernel<<<(N * 64 + 255) / 256, 256, 0, stream>>>(x1f, x1b, N * 64);
    // ---- layer 2 ----
    for (int n0 = 0; n0 < N; n0 += CH) {
        int nn = (N - n0 < CH) ? (N - n0) : CH;
        gather_mean_kernel<<<GA, 256, 0, stream>>>(x1b, es, rowptr, M, n0, nn);
        gemm_kernel<4, false><<<((nn + 15) / 16 + 3) / 4, 256, 0, stream>>>(
            M, wp2, b2, (float*)d_out, n0, nn);
    }
}

// Round 11
// 719.677 us; speedup vs baseline: 1.5402x; 1.5402x over previous
//
#include <hip/hip_runtime.h>

#define RR 8
#define DF 128
#define NPW 8          // nodes per wave (A rows 0..7; rows 8..15 zero)
#define SCAN_B 1024

typedef __attribute__((ext_vector_type(4))) float f32x4;
typedef __attribute__((ext_vector_type(8))) short sv8;
typedef sv8 __attribute__((may_alias)) sv8a;

__device__ __forceinline__ unsigned short bf16r(float f) {
    uint32_t u = __float_as_uint(f);
    u += 0x7fffu + ((u >> 16) & 1u);   // round-to-nearest-even
    return (unsigned short)(u >> 16);
}
__device__ __forceinline__ uint32_t packbf(float lo, float hi) {
    return (uint32_t)bf16r(lo) | ((uint32_t)bf16r(hi) << 16);
}

// ---------------- CSR build (proven) ----------------
__global__ void count_kernel(const int* __restrict__ tgt, const int* __restrict__ et,
                             int* __restrict__ cnt, int E) {
    int e = blockIdx.x * blockDim.x + threadIdx.x;
    if (e < E) atomicAdd(&cnt[tgt[e] * RR + et[e]], 1);
}

__global__ void scan_local(const int* __restrict__ in, int* __restrict__ excl,
                           int* __restrict__ bsum, int n) {
    __shared__ int sm[2][SCAN_B];
    int base = blockIdx.x * SCAN_B;
    for (int t = threadIdx.x; t < SCAN_B; t += 256) {
        int idx = base + t;
        sm[0][t] = (idx < n) ? in[idx] : 0;
    }
    __syncthreads();
    int pin = 0;
    for (int off = 1; off < SCAN_B; off <<= 1) {
        for (int t = threadIdx.x; t < SCAN_B; t += 256) {
            int v = sm[pin][t];
            if (t >= off) v += sm[pin][t - off];
            sm[pin ^ 1][t] = v;
        }
        __syncthreads();
        pin ^= 1;
    }
    for (int t = threadIdx.x; t < SCAN_B; t += 256) {
        int idx = base + t;
        if (idx < n) excl[idx] = sm[pin][t] - in[idx];
    }
    if (threadIdx.x == 0) bsum[blockIdx.x] = sm[pin][SCAN_B - 1];
}

__global__ void scan_bsum(int* __restrict__ bsum, int nb) {
    __shared__ int sm[512];
    for (int t = threadIdx.x; t < nb; t += 256) sm[t] = bsum[t];
    __syncthreads();
    if (threadIdx.x == 0) {
        int run = 0;
        for (int i = 0; i < nb; ++i) { int v = sm[i]; sm[i] = run; run += v; }
    }
    __syncthreads();
    for (int t = threadIdx.x; t < nb; t += 256) bsum[t] = sm[t];
}

__global__ void scan_finish(int* __restrict__ rowptr, const int* __restrict__ bsum,
                            int* __restrict__ cursor, int n, int E) {
    int i = blockIdx.x * blockDim.x + threadIdx.x;
    if (i < n) {
        int v = rowptr[i] + bsum[i / SCAN_B];
        rowptr[i] = v;
        cursor[i] = v;
    }
    if (i == 0) rowptr[n] = E;
}

__global__ void fill_kernel(const int* __restrict__ src, const int* __restrict__ tgt,
                            const int* __restrict__ et, int* __restrict__ cursor,
                            int* __restrict__ es, int E) {
    int e = blockIdx.x * blockDim.x + threadIdx.x;
    if (e < E) {
        int seg = tgt[e] * RR + et[e];
        int pos = atomicAdd(&cursor[seg], 1);
        es[pos] = src[e];
    }
}

// ---------------- f32 [n,2t] -> bf16-pair u32 [n,t] (proven) ----------------
__global__ void pack_x_kernel(const float* __restrict__ x, uint32_t* __restrict__ xb,
                              int n64) {
    int t = blockIdx.x * blockDim.x + threadIdx.x;
    if (t < n64) xb[t] = packbf(x[2 * t], x[2 * t + 1]);
}

// ---------------- W packing into MFMA B-fragment order (proven) ----------------
__global__ void pack_w_kernel(const float* __restrict__ W, const float* __restrict__ root,
                              unsigned short* __restrict__ wp, int NT) {
    int tid = blockIdx.x * blockDim.x + threadIdx.x;
    int total = 9 * NT * 2048;
    if (tid >= total) return;
    int i = tid & 7;
    int lane = (tid >> 3) & 63;
    int kk = (tid >> 9) & 3;
    int t = (tid >> 11) % NT;
    int rel = (tid >> 11) / NT;
    int k = kk * 32 + ((lane >> 4) << 3) + i;
    int col = t * 16 + (lane & 15);
    int dout = NT * 16;
    float v = (rel < RR) ? W[((long)rel * DF + k) * dout + col] : root[(long)k * dout + col];
    wp[tid] = bf16r(v);
}

// ---------------- fused gather-mean + MFMA transform ----------------
// r7 structure (proven: 44 VGPR, best total) with three changes:
//  1. gather source is bf16 [N,64] u32 (halves the random working set to
//     12.8MB -> much higher L2 hit rate on the 1.1TB/s-limited miss path);
//     2 edges/instruction x 32 lanes x uint2 = 512B/instr (2 full rows).
//  2. __launch_bounds__(256,8) pins VGPR<=64 (r6's regression was occupancy
//     lost to VGPR 68, not bf16).
//  3. es loads are non-temporal so the 6.4MB stream doesn't evict xb from L2.
template <int NT, bool RELU>
__global__ __launch_bounds__(256, 8) void fused_mfma_kernel(
    const uint32_t* __restrict__ xb,       // [N,64] bf16 pairs
    const int* __restrict__ es,            // segment-sorted src
    const int* __restrict__ rowptr,        // [N*R+1]
    const unsigned short* __restrict__ wp, // packed W frags
    const float* __restrict__ bias,        // [NT*16]
    float* __restrict__ out, int N) {
    __shared__ uint32_t a_sm[4][16][68];   // 16 rows x 136 bf16, wave-private
    const int wave = threadIdx.x >> 6;
    const int lane = threadIdx.x & 63;
    const int nb = (blockIdx.x * 4 + wave) * NPW;
    if (nb >= N) return;
    uint32_t(*A)[68] = a_sm[wave];

    for (int z = lane; z < 8 * 68; z += 64) (&A[8][0])[z] = 0u;  // rows 8..15 = 0

    const int j = lane;                    // u32 slot (root path)
    const int half = lane >> 5;            // 0: even edge, 1: odd edge
    const int f = lane & 31;               // uint2 slot (feats 4f..4f+3)
    const int arow = lane & 15;
    const int ag = lane >> 4;

    f32x4 acc[NT];
#pragma unroll
    for (int t = 0; t < NT; ++t) acc[t] = (f32x4){0.f, 0.f, 0.f, 0.f};

    for (int rel = 0; rel <= RR; ++rel) {
        if (rel < RR) {
            int e0[NPW], e1[NPW];
#pragma unroll
            for (int m = 0; m < NPW; ++m) {
                int seg = (nb + m) * RR + rel;
                e0[m] = rowptr[seg];
                e1[m] = rowptr[seg + 1];
            }
#pragma unroll 2
            for (int m = 0; m < NPW; ++m) {
                f32x4 v = {0.f, 0.f, 0.f, 0.f};
                for (int e = e0[m]; e < e1[m]; e += 2) {
                    int idx = e + half;
                    idx = (idx < e1[m]) ? idx : (e1[m] - 1);
                    int s = __builtin_nontemporal_load(es + idx);
                    uint2 u = *(const uint2*)(xb + (long)s * 64 + 2 * f);
                    bool ok = (e + half) < e1[m];
                    v.x += ok ? __uint_as_float(u.x << 16) : 0.f;
                    v.y += ok ? __uint_as_float(u.x & 0xffff0000u) : 0.f;
                    v.z += ok ? __uint_as_float(u.y << 16) : 0.f;
                    v.w += ok ? __uint_as_float(u.y & 0xffff0000u) : 0.f;
                }
                v.x += __shfl_xor(v.x, 32);
                v.y += __shfl_xor(v.y, 32);
                v.z += __shfl_xor(v.z, 32);
                v.w += __shfl_xor(v.w, 32);
                float inv = 1.f / fmaxf((float)(e1[m] - e0[m]), 1.f);
                if (half == 0) {
                    A[m][2 * f] = packbf(v.x * inv, v.y * inv);
                    A[m][2 * f + 1] = packbf(v.z * inv, v.w * inv);
                }
            }
        } else {
            // root "relation": A = raw input features (already bf16 pairs)
            for (int m = 0; m < NPW; ++m) A[m][j] = xb[(long)(nb + m) * 64 + j];
        }
        asm volatile("" ::: "memory");   // pin staging-writes before frag-reads
        sv8 af[4];                        // lane: A[arow][kk*32 + ag*8 .. +7]
#pragma unroll
        for (int kk = 0; kk < 4; ++kk)
            af[kk] = *(const sv8a*)&A[arow][kk * 16 + ag * 4];
        asm volatile("" ::: "memory");   // pin frag-reads before next staging
        const unsigned short* wr = wp + ((long)rel * NT << 11);
#pragma unroll
        for (int t = 0; t < NT; ++t) {
#pragma unroll
            for (int kk = 0; kk < 4; ++kk) {
                sv8 bf = *(const sv8a*)(wr + (((t * 4 + kk) << 9) + (lane << 3)));
                acc[t] = __builtin_amdgcn_mfma_f32_16x16x32_bf16(af[kk], bf, acc[t], 0, 0, 0);
            }
        }
    }

    // ---- epilogue: direct global stores (C/D map: col=lane&15, row=4*(lane>>4)+reg)
    constexpr int DOUT = NT * 16;
    if (lane < 32) {
#pragma unroll
        for (int t = 0; t < NT; ++t) {
            int col = t * 16 + (lane & 15);
            float bv = bias[col];
#pragma unroll
            for (int reg = 0; reg < 4; ++reg) {
                int row = ((lane >> 4) << 2) + reg;   // 0..7
                float v = acc[t][reg] + bv;
                if (RELU) v = fmaxf(v, 0.f);
                out[(long)(nb + row) * DOUT + col] = v;
            }
        }
    }
}

extern "C" void kernel_launch(void* const* d_in, const int* in_sizes, int n_in,
                              void* d_out, int out_size, void* d_ws, size_t ws_size,
                              hipStream_t stream) {
    const float* xf = (const float*)d_in[0];
    const float* W1 = (const float*)d_in[1];
    const float* r1 = (const float*)d_in[2];
    const float* b1 = (const float*)d_in[3];
    const float* W2 = (const float*)d_in[4];
    const float* r2 = (const float*)d_in[5];
    const float* b2 = (const float*)d_in[6];
    const int* eidx = (const int*)d_in[7];
    const int* etyp = (const int*)d_in[8];
    const int N = in_sizes[0] / DF;
    const int E = in_sizes[8];
    const int* src = eidx;
    const int* tgt = eidx + E;
    const int NR = N * RR;

    // ws: cnt[NR] rowptr[NR+16] cursor[NR+16] bsum[512] es[E]
    //     x1f[N*128]f32 xb[N*64]u32 x1b[N*64]u32 wp1 wp2
    int* cnt = (int*)d_ws;
    int* rowptr = cnt + NR;
    int* cursor = rowptr + NR + 16;
    int* bsum = cursor + NR + 16;
    int* es = bsum + 512;
    float* x1f = (float*)(es + E);
    uint32_t* xb = (uint32_t*)(x1f + (size_t)N * DF);
    uint32_t* x1b = xb + (size_t)N * 64;
    unsigned short* wp1 = (unsigned short*)(x1b + (size_t)N * 64);
    unsigned short* wp2 = wp1 + 9 * 8 * 2048;

    const int nb1 = (NR + SCAN_B - 1) / SCAN_B;

    hipMemsetAsync(cnt, 0, (size_t)NR * sizeof(int), stream);
    count_kernel<<<(E + 255) / 256, 256, 0, stream>>>(tgt, etyp, cnt, E);
    scan_local<<<nb1, 256, 0, stream>>>(cnt, rowptr, bsum, NR);
    scan_bsum<<<1, 256, 0, stream>>>(bsum, nb1);
    scan_finish<<<(NR + 255) / 256, 256, 0, stream>>>(rowptr, bsum, cursor, NR, E);
    fill_kernel<<<(E + 255) / 256, 256, 0, stream>>>(src, tgt, etyp, cursor, es, E);

    pack_x_kernel<<<(N * 64 + 255) / 256, 256, 0, stream>>>(xf, xb, N * 64);
    pack_w_kernel<<<(9 * 8 * 2048 + 255) / 256, 256, 0, stream>>>(W1, r1, wp1, 8);
    pack_w_kernel<<<(9 * 4 * 2048 + 255) / 256, 256, 0, stream>>>(W2, r2, wp2, 4);

    const int fblocks = (N / NPW + 3) / 4;
    // layer 1: xb -> x1f (f32), relu
    fused_mfma_kernel<8, true><<<fblocks, 256, 0, stream>>>(
        xb, es, rowptr, wp1, b1, x1f, N);
    // repack to bf16 for layer-2 gather
    pack_x_kernel<<<(N * 64 + 255) / 256, 256, 0, stream>>>(x1f, x1b, N * 64);
    // layer 2: x1b -> d_out (f32)
    fused_mfma_kernel<4, false><<<fblocks, 256, 0, stream>>>(
        x1b, es, rowptr, wp2, b2, (float*)d_out, N);
}

// Round 12
// 648.301 us; speedup vs baseline: 1.7097x; 1.1101x over previous
//
#include <hip/hip_runtime.h>

#define RR 8
#define DF 128
#define NPW 8          // nodes per wave (A rows 0..7; rows 8..15 zero)
#define SCAN_B 1024

typedef __attribute__((ext_vector_type(4))) float f32x4;
typedef __attribute__((ext_vector_type(8))) short sv8;
typedef sv8 __attribute__((may_alias)) sv8a;

__device__ __forceinline__ unsigned short bf16r(float f) {
    uint32_t u = __float_as_uint(f);
    u += 0x7fffu + ((u >> 16) & 1u);   // round-to-nearest-even
    return (unsigned short)(u >> 16);
}
__device__ __forceinline__ uint32_t packbf(float lo, float hi) {
    return (uint32_t)bf16r(lo) | ((uint32_t)bf16r(hi) << 16);
}

// ---------------- CSR build ----------------
// count also emits each edge's rank within its segment (the atomic's return
// value) so fill needs NO atomics.
__global__ void count_kernel(const int* __restrict__ tgt, const int* __restrict__ et,
                             int* __restrict__ cnt, unsigned short* __restrict__ rank16,
                             int E) {
    int e = blockIdx.x * blockDim.x + threadIdx.x;
    if (e < E) rank16[e] = (unsigned short)atomicAdd(&cnt[tgt[e] * RR + et[e]], 1);
}

__global__ void scan_local(const int* __restrict__ in, int* __restrict__ excl,
                           int* __restrict__ bsum, int n) {
    __shared__ int sm[2][SCAN_B];
    int base = blockIdx.x * SCAN_B;
    for (int t = threadIdx.x; t < SCAN_B; t += 256) {
        int idx = base + t;
        sm[0][t] = (idx < n) ? in[idx] : 0;
    }
    __syncthreads();
    int pin = 0;
    for (int off = 1; off < SCAN_B; off <<= 1) {
        for (int t = threadIdx.x; t < SCAN_B; t += 256) {
            int v = sm[pin][t];
            if (t >= off) v += sm[pin][t - off];
            sm[pin ^ 1][t] = v;
        }
        __syncthreads();
        pin ^= 1;
    }
    for (int t = threadIdx.x; t < SCAN_B; t += 256) {
        int idx = base + t;
        if (idx < n) excl[idx] = sm[pin][t] - in[idx];
    }
    if (threadIdx.x == 0) bsum[blockIdx.x] = sm[pin][SCAN_B - 1];
}

__global__ void scan_bsum(int* __restrict__ bsum, int nb) {
    __shared__ int sm[512];
    for (int t = threadIdx.x; t < nb; t += 256) sm[t] = bsum[t];
    __syncthreads();
    if (threadIdx.x == 0) {
        int run = 0;
        for (int i = 0; i < nb; ++i) { int v = sm[i]; sm[i] = run; run += v; }
    }
    __syncthreads();
    for (int t = threadIdx.x; t < nb; t += 256) bsum[t] = sm[t];
}

__global__ void scan_finish(int* __restrict__ rowptr, const int* __restrict__ bsum,
                            int n, int E) {
    int i = blockIdx.x * blockDim.x + threadIdx.x;
    if (i < n) rowptr[i] = rowptr[i] + bsum[i / SCAN_B];
    if (i == 0) rowptr[n] = E;
}

// atomic-free fill: position = rowptr[seg] + rank16[e]; es is ushort (src<65536)
__global__ void fill_kernel(const int* __restrict__ src, const int* __restrict__ tgt,
                            const int* __restrict__ et,
                            const unsigned short* __restrict__ rank16,
                            const int* __restrict__ rowptr,
                            unsigned short* __restrict__ es, int E) {
    int e = blockIdx.x * blockDim.x + threadIdx.x;
    if (e < E) {
        int seg = tgt[e] * RR + et[e];
        es[rowptr[seg] + (int)rank16[e]] = (unsigned short)src[e];
    }
}

// ---------------- f32 [n,2t] -> bf16-pair u32 [n,t] (proven) ----------------
__global__ void pack_x_kernel(const float* __restrict__ x, uint32_t* __restrict__ xb,
                              int n64) {
    int t = blockIdx.x * blockDim.x + threadIdx.x;
    if (t < n64) xb[t] = packbf(x[2 * t], x[2 * t + 1]);
}

// ---------------- W packing into MFMA B-fragment order (proven) ----------------
__global__ void pack_w_kernel(const float* __restrict__ W, const float* __restrict__ root,
                              unsigned short* __restrict__ wp, int NT) {
    int tid = blockIdx.x * blockDim.x + threadIdx.x;
    int total = 9 * NT * 2048;
    if (tid >= total) return;
    int i = tid & 7;
    int lane = (tid >> 3) & 63;
    int kk = (tid >> 9) & 3;
    int t = (tid >> 11) % NT;
    int rel = (tid >> 11) / NT;
    int k = kk * 32 + ((lane >> 4) << 3) + i;
    int col = t * 16 + (lane & 15);
    int dout = NT * 16;
    float v = (rel < RR) ? W[((long)rel * DF + k) * dout + col] : root[(long)k * dout + col];
    wp[tid] = bf16r(v);
}

// ---------------- fused gather-mean + MFMA transform (r11-proven) ----------------
template <int NT, bool RELU>
__global__ __launch_bounds__(256, 8) void fused_mfma_kernel(
    const uint32_t* __restrict__ xb,       // [N,64] bf16 pairs
    const unsigned short* __restrict__ es, // segment-sorted src (u16)
    const int* __restrict__ rowptr,        // [N*R+1]
    const unsigned short* __restrict__ wp, // packed W frags
    const float* __restrict__ bias,        // [NT*16]
    float* __restrict__ out, int N) {
    __shared__ uint32_t a_sm[4][16][68];   // 16 rows x 136 bf16, wave-private
    const int wave = threadIdx.x >> 6;
    const int lane = threadIdx.x & 63;
    const int nb = (blockIdx.x * 4 + wave) * NPW;
    if (nb >= N) return;
    uint32_t(*A)[68] = a_sm[wave];

    for (int z = lane; z < 8 * 68; z += 64) (&A[8][0])[z] = 0u;  // rows 8..15 = 0

    const int j = lane;                    // u32 slot (root path)
    const int half = lane >> 5;            // 0: even edge, 1: odd edge
    const int f = lane & 31;               // uint2 slot (feats 4f..4f+3)
    const int arow = lane & 15;
    const int ag = lane >> 4;

    f32x4 acc[NT];
#pragma unroll
    for (int t = 0; t < NT; ++t) acc[t] = (f32x4){0.f, 0.f, 0.f, 0.f};

    for (int rel = 0; rel <= RR; ++rel) {
        if (rel < RR) {
            int e0[NPW], e1[NPW];
#pragma unroll
            for (int m = 0; m < NPW; ++m) {
                int seg = (nb + m) * RR + rel;
                e0[m] = rowptr[seg];
                e1[m] = rowptr[seg + 1];
            }
#pragma unroll 2
            for (int m = 0; m < NPW; ++m) {
                f32x4 v = {0.f, 0.f, 0.f, 0.f};
                for (int e = e0[m]; e < e1[m]; e += 2) {
                    int idx = e + half;
                    idx = (idx < e1[m]) ? idx : (e1[m] - 1);
                    int s = (int)__builtin_nontemporal_load(es + idx);
                    uint2 u = *(const uint2*)(xb + (long)s * 64 + 2 * f);
                    bool ok = (e + half) < e1[m];
                    v.x += ok ? __uint_as_float(u.x << 16) : 0.f;
                    v.y += ok ? __uint_as_float(u.x & 0xffff0000u) : 0.f;
                    v.z += ok ? __uint_as_float(u.y << 16) : 0.f;
                    v.w += ok ? __uint_as_float(u.y & 0xffff0000u) : 0.f;
                }
                v.x += __shfl_xor(v.x, 32);
                v.y += __shfl_xor(v.y, 32);
                v.z += __shfl_xor(v.z, 32);
                v.w += __shfl_xor(v.w, 32);
                float inv = 1.f / fmaxf((float)(e1[m] - e0[m]), 1.f);
                if (half == 0) {
                    A[m][2 * f] = packbf(v.x * inv, v.y * inv);
                    A[m][2 * f + 1] = packbf(v.z * inv, v.w * inv);
                }
            }
        } else {
            // root "relation": A = raw input features (already bf16 pairs)
            for (int m = 0; m < NPW; ++m) A[m][j] = xb[(long)(nb + m) * 64 + j];
        }
        asm volatile("" ::: "memory");   // pin staging-writes before frag-reads
        sv8 af[4];                        // lane: A[arow][kk*32 + ag*8 .. +7]
#pragma unroll
        for (int kk = 0; kk < 4; ++kk)
            af[kk] = *(const sv8a*)&A[arow][kk * 16 + ag * 4];
        asm volatile("" ::: "memory");   // pin frag-reads before next staging
        const unsigned short* wr = wp + ((long)rel * NT << 11);
#pragma unroll
        for (int t = 0; t < NT; ++t) {
#pragma unroll
            for (int kk = 0; kk < 4; ++kk) {
                sv8 bf = *(const sv8a*)(wr + (((t * 4 + kk) << 9) + (lane << 3)));
                acc[t] = __builtin_amdgcn_mfma_f32_16x16x32_bf16(af[kk], bf, acc[t], 0, 0, 0);
            }
        }
    }

    // ---- epilogue: direct global stores (C/D map: col=lane&15, row=4*(lane>>4)+reg)
    constexpr int DOUT = NT * 16;
    if (lane < 32) {
#pragma unroll
        for (int t = 0; t < NT; ++t) {
            int col = t * 16 + (lane & 15);
            float bv = bias[col];
#pragma unroll
            for (int reg = 0; reg < 4; ++reg) {
                int row = ((lane >> 4) << 2) + reg;   // 0..7
                float v = acc[t][reg] + bv;
                if (RELU) v = fmaxf(v, 0.f);
                out[(long)(nb + row) * DOUT + col] = v;
            }
        }
    }
}

extern "C" void kernel_launch(void* const* d_in, const int* in_sizes, int n_in,
                              void* d_out, int out_size, void* d_ws, size_t ws_size,
                              hipStream_t stream) {
    const float* xf = (const float*)d_in[0];
    const float* W1 = (const float*)d_in[1];
    const float* r1 = (const float*)d_in[2];
    const float* b1 = (const float*)d_in[3];
    const float* W2 = (const float*)d_in[4];
    const float* r2 = (const float*)d_in[5];
    const float* b2 = (const float*)d_in[6];
    const int* eidx = (const int*)d_in[7];
    const int* etyp = (const int*)d_in[8];
    const int N = in_sizes[0] / DF;
    const int E = in_sizes[8];
    const int* src = eidx;
    const int* tgt = eidx + E;
    const int NR = N * RR;

    // ws: cnt[NR] rowptr[NR+16] bsum[512] rank16[E] es16[E]
    //     x1f[N*128]f32 xb[N*64]u32 x1b[N*64]u32 wp1 wp2   (~62 MB)
    int* cnt = (int*)d_ws;
    int* rowptr = cnt + NR;
    int* bsum = rowptr + NR + 16;
    unsigned short* rank16 = (unsigned short*)(bsum + 512);
    unsigned short* es16 = rank16 + E;
    float* x1f = (float*)(es16 + E);
    uint32_t* xb = (uint32_t*)(x1f + (size_t)N * DF);
    uint32_t* x1b = xb + (size_t)N * 64;
    unsigned short* wp1 = (unsigned short*)(x1b + (size_t)N * 64);
    unsigned short* wp2 = wp1 + 9 * 8 * 2048;

    const int nb1 = (NR + SCAN_B - 1) / SCAN_B;

    hipMemsetAsync(cnt, 0, (size_t)NR * sizeof(int), stream);
    count_kernel<<<(E + 255) / 256, 256, 0, stream>>>(tgt, etyp, cnt, rank16, E);
    scan_local<<<nb1, 256, 0, stream>>>(cnt, rowptr, bsum, NR);
    scan_bsum<<<1, 256, 0, stream>>>(bsum, nb1);
    scan_finish<<<(NR + 255) / 256, 256, 0, stream>>>(rowptr, bsum, NR, E);
    fill_kernel<<<(E + 255) / 256, 256, 0, stream>>>(src, tgt, etyp, rank16, rowptr,
                                                     es16, E);

    pack_x_kernel<<<(N * 64 + 255) / 256, 256, 0, stream>>>(xf, xb, N * 64);
    pack_w_kernel<<<(9 * 8 * 2048 + 255) / 256, 256, 0, stream>>>(W1, r1, wp1, 8);
    pack_w_kernel<<<(9 * 4 * 2048 + 255) / 256, 256, 0, stream>>>(W2, r2, wp2, 4);

    const int fblocks = (N / NPW + 3) / 4;
    // layer 1: xb -> x1f (f32), relu
    fused_mfma_kernel<8, true><<<fblocks, 256, 0, stream>>>(
        xb, es16, rowptr, wp1, b1, x1f, N);
    // repack to bf16 for layer-2 gather
    pack_x_kernel<<<(N * 64 + 255) / 256, 256, 0, stream>>>(x1f, x1b, N * 64);
    // layer 2: x1b -> d_out (f32)
    fused_mfma_kernel<4, false><<<fblocks, 256, 0, stream>>>(
        x1b, es16, rowptr, wp2, b2, (float*)d_out, N);
}

// Round 13
// 551.521 us; speedup vs baseline: 2.0098x; 1.1755x over previous
//
#include <hip/hip_runtime.h>

#define RR 8
#define DF 128
#define NPW 8          // nodes per wave (A rows 0..7; rows 8..15 zero)
#define SCAN_B 1024

typedef __attribute__((ext_vector_type(4))) float f32x4;
typedef __attribute__((ext_vector_type(8))) short sv8;
typedef sv8 __attribute__((may_alias)) sv8a;

__device__ __forceinline__ unsigned short bf16r(float f) {
    uint32_t u = __float_as_uint(f);
    u += 0x7fffu + ((u >> 16) & 1u);   // round-to-nearest-even
    return (unsigned short)(u >> 16);
}
__device__ __forceinline__ uint32_t packbf(float lo, float hi) {
    return (uint32_t)bf16r(lo) | ((uint32_t)bf16r(hi) << 16);
}

// ---------------- CSR build (r12-proven: atomic-free fill) ----------------
__global__ void count_kernel(const int* __restrict__ tgt, const int* __restrict__ et,
                             int* __restrict__ cnt, unsigned short* __restrict__ rank16,
                             int E) {
    int e = blockIdx.x * blockDim.x + threadIdx.x;
    if (e < E) rank16[e] = (unsigned short)atomicAdd(&cnt[tgt[e] * RR + et[e]], 1);
}

__global__ void scan_local(const int* __restrict__ in, int* __restrict__ excl,
                           int* __restrict__ bsum, int n) {
    __shared__ int sm[2][SCAN_B];
    int base = blockIdx.x * SCAN_B;
    for (int t = threadIdx.x; t < SCAN_B; t += 256) {
        int idx = base + t;
        sm[0][t] = (idx < n) ? in[idx] : 0;
    }
    __syncthreads();
    int pin = 0;
    for (int off = 1; off < SCAN_B; off <<= 1) {
        for (int t = threadIdx.x; t < SCAN_B; t += 256) {
            int v = sm[pin][t];
            if (t >= off) v += sm[pin][t - off];
            sm[pin ^ 1][t] = v;
        }
        __syncthreads();
        pin ^= 1;
    }
    for (int t = threadIdx.x; t < SCAN_B; t += 256) {
        int idx = base + t;
        if (idx < n) excl[idx] = sm[pin][t] - in[idx];
    }
    if (threadIdx.x == 0) bsum[blockIdx.x] = sm[pin][SCAN_B - 1];
}

__global__ void scan_bsum(int* __restrict__ bsum, int nb) {
    __shared__ int sm[512];
    for (int t = threadIdx.x; t < nb; t += 256) sm[t] = bsum[t];
    __syncthreads();
    if (threadIdx.x == 0) {
        int run = 0;
        for (int i = 0; i < nb; ++i) { int v = sm[i]; sm[i] = run; run += v; }
    }
    __syncthreads();
    for (int t = threadIdx.x; t < nb; t += 256) bsum[t] = sm[t];
}

__global__ void scan_finish(int* __restrict__ rowptr, const int* __restrict__ bsum,
                            int n, int E) {
    int i = blockIdx.x * blockDim.x + threadIdx.x;
    if (i < n) rowptr[i] = rowptr[i] + bsum[i / SCAN_B];
    if (i == 0) rowptr[n] = E;
}

__global__ void fill_kernel(const int* __restrict__ src, const int* __restrict__ tgt,
                            const int* __restrict__ et,
                            const unsigned short* __restrict__ rank16,
                            const int* __restrict__ rowptr,
                            unsigned short* __restrict__ es, int E) {
    int e = blockIdx.x * blockDim.x + threadIdx.x;
    if (e < E) {
        int seg = tgt[e] * RR + et[e];
        es[rowptr[seg] + (int)rank16[e]] = (unsigned short)src[e];
    }
}

// ---------------- f32 [n,2t] -> bf16-pair u32 [n,t] (proven) ----------------
__global__ void pack_x_kernel(const float* __restrict__ x, uint32_t* __restrict__ xb,
                              int n64) {
    int t = blockIdx.x * blockDim.x + threadIdx.x;
    if (t < n64) xb[t] = packbf(x[2 * t], x[2 * t + 1]);
}

// ---------------- W packing into MFMA B-fragment order (proven) ----------------
__global__ void pack_w_kernel(const float* __restrict__ W, const float* __restrict__ root,
                              unsigned short* __restrict__ wp, int NT) {
    int tid = blockIdx.x * blockDim.x + threadIdx.x;
    int total = 9 * NT * 2048;
    if (tid >= total) return;
    int i = tid & 7;
    int lane = (tid >> 3) & 63;
    int kk = (tid >> 9) & 3;
    int t = (tid >> 11) % NT;
    int rel = (tid >> 11) / NT;
    int k = kk * 32 + ((lane >> 4) << 3) + i;
    int col = t * 16 + (lane & 15);
    int dout = NT * 16;
    float v = (rel < RR) ? W[((long)rel * DF + k) * dout + col] : root[(long)k * dout + col];
    wp[tid] = bf16r(v);
}

// ---------------- fused gather-mean + MFMA transform ----------------
// r12 structure; changes: (1) es loads CACHED (nt dropped: es is sequential,
// nt caused ~64MB/layer of line refetch); (2) OUTBF path packs the epilogue
// to bf16 in-register (shfl_xor(1) col-pair exchange, even lanes store u32),
// eliminating the f32 intermediate + repack pass for layer 1.
template <int NT, bool RELU, bool OUTBF>
__global__ __launch_bounds__(256, 8) void fused_mfma_kernel(
    const uint32_t* __restrict__ xb,       // [N,64] bf16 pairs
    const unsigned short* __restrict__ es, // segment-sorted src (u16)
    const int* __restrict__ rowptr,        // [N*R+1]
    const unsigned short* __restrict__ wp, // packed W frags
    const float* __restrict__ bias,        // [NT*16]
    void* __restrict__ outp, int N) {
    __shared__ uint32_t a_sm[4][16][68];   // 16 rows x 136 bf16, wave-private
    const int wave = threadIdx.x >> 6;
    const int lane = threadIdx.x & 63;
    const int nb = (blockIdx.x * 4 + wave) * NPW;
    if (nb >= N) return;
    uint32_t(*A)[68] = a_sm[wave];

    for (int z = lane; z < 8 * 68; z += 64) (&A[8][0])[z] = 0u;  // rows 8..15 = 0

    const int j = lane;                    // u32 slot (root path)
    const int half = lane >> 5;            // 0: even edge, 1: odd edge
    const int f = lane & 31;               // uint2 slot (feats 4f..4f+3)
    const int arow = lane & 15;
    const int ag = lane >> 4;

    f32x4 acc[NT];
#pragma unroll
    for (int t = 0; t < NT; ++t) acc[t] = (f32x4){0.f, 0.f, 0.f, 0.f};

    for (int rel = 0; rel <= RR; ++rel) {
        if (rel < RR) {
            int e0[NPW], e1[NPW];
#pragma unroll
            for (int m = 0; m < NPW; ++m) {
                int seg = (nb + m) * RR + rel;
                e0[m] = rowptr[seg];
                e1[m] = rowptr[seg + 1];
            }
#pragma unroll 2
            for (int m = 0; m < NPW; ++m) {
                f32x4 v = {0.f, 0.f, 0.f, 0.f};
                for (int e = e0[m]; e < e1[m]; e += 2) {
                    int idx = e + half;
                    idx = (idx < e1[m]) ? idx : (e1[m] - 1);
                    int s = (int)es[idx];
                    uint2 u = *(const uint2*)(xb + (long)s * 64 + 2 * f);
                    bool ok = (e + half) < e1[m];
                    v.x += ok ? __uint_as_float(u.x << 16) : 0.f;
                    v.y += ok ? __uint_as_float(u.x & 0xffff0000u) : 0.f;
                    v.z += ok ? __uint_as_float(u.y << 16) : 0.f;
                    v.w += ok ? __uint_as_float(u.y & 0xffff0000u) : 0.f;
                }
                v.x += __shfl_xor(v.x, 32);
                v.y += __shfl_xor(v.y, 32);
                v.z += __shfl_xor(v.z, 32);
                v.w += __shfl_xor(v.w, 32);
                float inv = 1.f / fmaxf((float)(e1[m] - e0[m]), 1.f);
                if (half == 0) {
                    A[m][2 * f] = packbf(v.x * inv, v.y * inv);
                    A[m][2 * f + 1] = packbf(v.z * inv, v.w * inv);
                }
            }
        } else {
            // root "relation": A = raw input features (already bf16 pairs)
            for (int m = 0; m < NPW; ++m) A[m][j] = xb[(long)(nb + m) * 64 + j];
        }
        asm volatile("" ::: "memory");   // pin staging-writes before frag-reads
        sv8 af[4];                        // lane: A[arow][kk*32 + ag*8 .. +7]
#pragma unroll
        for (int kk = 0; kk < 4; ++kk)
            af[kk] = *(const sv8a*)&A[arow][kk * 16 + ag * 4];
        asm volatile("" ::: "memory");   // pin frag-reads before next staging
        const unsigned short* wr = wp + ((long)rel * NT << 11);
#pragma unroll
        for (int t = 0; t < NT; ++t) {
#pragma unroll
            for (int kk = 0; kk < 4; ++kk) {
                sv8 bf = *(const sv8a*)(wr + (((t * 4 + kk) << 9) + (lane << 3)));
                acc[t] = __builtin_amdgcn_mfma_f32_16x16x32_bf16(af[kk], bf, acc[t], 0, 0, 0);
            }
        }
    }

    // ---- epilogue (C/D map: col=lane&15, row=4*(lane>>4)+reg, rows 0..7 real)
    constexpr int DOUT = NT * 16;
    if (lane < 32) {
        if (OUTBF) {
            uint32_t* ob = (uint32_t*)outp;   // [N, DOUT/2] bf16 pairs
#pragma unroll
            for (int t = 0; t < NT; ++t) {
                int col = t * 16 + (lane & 15);
                float bv = bias[col];
#pragma unroll
                for (int reg = 0; reg < 4; ++reg) {
                    int row = ((lane >> 4) << 2) + reg;   // 0..7
                    float v = acc[t][reg] + bv;
                    if (RELU) v = fmaxf(v, 0.f);
                    float vp = __shfl_xor(v, 1);          // partner col value
                    if (!(lane & 1))
                        ob[(long)(nb + row) * (DOUT / 2) + (col >> 1)] = packbf(v, vp);
                }
            }
        } else {
            float* of = (float*)outp;         // [N, DOUT] f32
#pragma unroll
            for (int t = 0; t < NT; ++t) {
                int col = t * 16 + (lane & 15);
                float bv = bias[col];
#pragma unroll
                for (int reg = 0; reg < 4; ++reg) {
                    int row = ((lane >> 4) << 2) + reg;   // 0..7
                    float v = acc[t][reg] + bv;
                    if (RELU) v = fmaxf(v, 0.f);
                    of[(long)(nb + row) * DOUT + col] = v;
                }
            }
        }
    }
}

extern "C" void kernel_launch(void* const* d_in, const int* in_sizes, int n_in,
                              void* d_out, int out_size, void* d_ws, size_t ws_size,
                              hipStream_t stream) {
    const float* xf = (const float*)d_in[0];
    const float* W1 = (const float*)d_in[1];
    const float* r1 = (const float*)d_in[2];
    const float* b1 = (const float*)d_in[3];
    const float* W2 = (const float*)d_in[4];
    const float* r2 = (const float*)d_in[5];
    const float* b2 = (const float*)d_in[6];
    const int* eidx = (const int*)d_in[7];
    const int* etyp = (const int*)d_in[8];
    const int N = in_sizes[0] / DF;
    const int E = in_sizes[8];
    const int* src = eidx;
    const int* tgt = eidx + E;
    const int NR = N * RR;

    // ws: cnt[NR] rowptr[NR+16] bsum[512] rank16[E] es16[E]
    //     xb[N*64]u32 x1b[N*64]u32 wp1 wp2   (~37 MB)
    int* cnt = (int*)d_ws;
    int* rowptr = cnt + NR;
    int* bsum = rowptr + NR + 16;
    unsigned short* rank16 = (unsigned short*)(bsum + 512);
    unsigned short* es16 = rank16 + E;
    uint32_t* xb = (uint32_t*)(es16 + E);
    uint32_t* x1b = xb + (size_t)N * 64;
    unsigned short* wp1 = (unsigned short*)(x1b + (size_t)N * 64);
    unsigned short* wp2 = wp1 + 9 * 8 * 2048;

    const int nb1 = (NR + SCAN_B - 1) / SCAN_B;

    hipMemsetAsync(cnt, 0, (size_t)NR * sizeof(int), stream);
    count_kernel<<<(E + 255) / 256, 256, 0, stream>>>(tgt, etyp, cnt, rank16, E);
    scan_local<<<nb1, 256, 0, stream>>>(cnt, rowptr, bsum, NR);
    scan_bsum<<<1, 256, 0, stream>>>(bsum, nb1);
    scan_finish<<<(NR + 255) / 256, 256, 0, stream>>>(rowptr, bsum, NR, E);
    fill_kernel<<<(E + 255) / 256, 256, 0, stream>>>(src, tgt, etyp, rank16, rowptr,
                                                     es16, E);

    pack_x_kernel<<<(N * 64 + 255) / 256, 256, 0, stream>>>(xf, xb, N * 64);
    pack_w_kernel<<<(9 * 8 * 2048 + 255) / 256, 256, 0, stream>>>(W1, r1, wp1, 8);
    pack_w_kernel<<<(9 * 4 * 2048 + 255) / 256, 256, 0, stream>>>(W2, r2, wp2, 4);

    const int fblocks = (N / NPW + 3) / 4;
    // layer 1: xb -> x1b (bf16 direct), relu
    fused_mfma_kernel<8, true, true><<<fblocks, 256, 0, stream>>>(
        xb, es16, rowptr, wp1, b1, x1b, N);
    // layer 2: x1b -> d_out (f32)
    fused_mfma_kernel<4, false, false><<<fblocks, 256, 0, stream>>>(
        x1b, es16, rowptr, wp2, b2, d_out, N);
}